// Round 5
// baseline (891.121 us; speedup 1.0000x reference)
//
#include <hip/hip_runtime.h>
#include <cstdint>
#include <cstddef>

// ---------------------------------------------------------------------------
// GraphMathSolver: 4-layer MPNN on MI355X.
// Round 5: k_msg -> 128-edge tile, 512 threads, T3-min 2-phase pipeline
//   (stage-next before MFMA, single barrier per chunk). agg zeroing fused
//   into k_upd; pool+readout fused. Sorted-edge segmented reduce kept.
// ---------------------------------------------------------------------------

typedef unsigned short u16;
typedef __attribute__((ext_vector_type(4))) float f32x4;
typedef __attribute__((ext_vector_type(8))) short bf16x8;
typedef __attribute__((ext_vector_type(4))) short s16x4;

constexpr int kN  = 10000;
constexpr int kE  = 160000;
constexpr int kB  = 64;
constexpr int kH  = 256;
constexpr int kL  = 4;
constexpr int kC  = 10;
constexpr float kEps = 1e-5f;

struct __align__(16) F4 { float v[4]; };
__device__ __forceinline__ F4 ldF4(const float* p) { return *reinterpret_cast<const F4*>(p); }

__device__ __forceinline__ u16 f2bf(float f) {
    unsigned u = __builtin_bit_cast(unsigned, f);
    return (u16)((u + 0x7fffu + ((u >> 16) & 1u)) >> 16);
}
__device__ __forceinline__ float bf2f(u16 h) {
    return __builtin_bit_cast(float, (unsigned)h << 16);
}

// ---- async global->LDS DMA, 16B per lane (lds base wave-uniform) ----------
typedef __attribute__((address_space(1))) void GV;
typedef __attribute__((address_space(3))) void LV;
__device__ __forceinline__ void gl_lds16(const void* g, void* l) {
    __builtin_amdgcn_global_load_lds((GV*)g, (LV*)l, 16, 0, 0);
}
// 256-thread variant: 16KB chunk, 4 waves x 4KB
__device__ __forceinline__ void dma_w16k(const u16* __restrict__ Wc, char* lds, int tid) {
    const int w = tid >> 6, lane = tid & 63;
    char* lb = lds + w * 4096;
    const char* gb = (const char*)Wc + w * 4096 + lane * 16;
    #pragma unroll
    for (int i = 0; i < 4; ++i) gl_lds16(gb + i * 1024, lb + i * 1024);
}

// ---------------- int64/int32 index handling (ref uses jnp.int64) ----------
__global__ void k_detect_i64(const unsigned* __restrict__ w, int* __restrict__ flag) {
    if (threadIdx.x == 0 && blockIdx.x == 0) {
        int is64 = 1;
        for (int i = 0; i < 64; ++i)
            if (w[2*i + 1] != 0u) { is64 = 0; break; }
        *flag = is64;
    }
}
__global__ void k_cvt_idx(const unsigned* __restrict__ w, const int* __restrict__ flag,
                          int* __restrict__ out, int n) {
    int i = blockIdx.x * 256 + threadIdx.x;
    if (i < n) out[i] = (*flag) ? (int)w[2*i] : (int)w[i];
}

// ---------------- counting sort of edges by dst -----------------------------
__global__ __launch_bounds__(256) void k_hist(const int* __restrict__ dst,
                                              int* __restrict__ cnt) {
    int e = blockIdx.x * 256 + threadIdx.x;
    if (e < kE) atomicAdd(&cnt[dst[e]], 1);
}
__global__ __launch_bounds__(256) void k_scan(const int* __restrict__ cnt,
                                              int* __restrict__ cur) {
    __shared__ int part[256];
    const int t = threadIdx.x;
    const int per = (kN + 255) / 256;
    int s = 0;
    for (int i = 0; i < per; ++i) {
        int idx = t * per + i;
        if (idx < kN) s += cnt[idx];
    }
    int own = s;
    part[t] = s; __syncthreads();
    for (int off = 1; off < 256; off <<= 1) {
        int v = (t >= off) ? part[t - off] : 0;
        __syncthreads();
        part[t] += v;
        __syncthreads();
    }
    int run = part[t] - own;
    for (int i = 0; i < per; ++i) {
        int idx = t * per + i;
        if (idx < kN) { cur[idx] = run; run += cnt[idx]; }
    }
}
__global__ __launch_bounds__(256) void k_scatter(
    const int* __restrict__ src, const int* __restrict__ dst,
    int* __restrict__ cur, int* __restrict__ perm,
    int* __restrict__ ssorted, int* __restrict__ dsorted) {
    int e = blockIdx.x * 256 + threadIdx.x;
    if (e < kE) {
        int d = dst[e];
        int p = atomicAdd(&cur[d], 1);
        perm[p] = e;
        ssorted[p] = src[e];
        dsorted[p] = d;
    }
}

// ---- weight prep: fp32 [L][K][256] -> bf16 swizzled-linear [L][kc][n][32] --
__global__ __launch_bounds__(256) void k_prep_w(
    const float* __restrict__ mW1, const float* __restrict__ mW2,
    const float* __restrict__ uW1, const float* __restrict__ uW2,
    const float* __restrict__ eW,
    u16* __restrict__ tm1, u16* __restrict__ tm2,
    u16* __restrict__ tu1, u16* __restrict__ tu2, u16* __restrict__ te)
{
    int idx = blockIdx.x * 256 + threadIdx.x;
    const int S1 = kL * 768 * 256;
    const int S2 = S1 + kL * 256 * 256;
    const int S3 = S2 + kL * 512 * 256;
    const int S4 = S3 + kL * 256 * 256;
    const int S5 = S4 + 64 * 256;
    const float* src; u16* dst; int K, r;
    if (idx < S1)      { src = mW1; dst = tm1; K = 768; r = idx; }
    else if (idx < S2) { src = mW2; dst = tm2; K = 256; r = idx - S1; }
    else if (idx < S3) { src = uW1; dst = tu1; K = 512; r = idx - S2; }
    else if (idx < S4) { src = uW2; dst = tu2; K = 256; r = idx - S3; }
    else if (idx < S5) { src = eW;  dst = te;  K = 64;  r = idx - S4; }
    else return;
    int per = K * 256;
    int layer = r / per, rr = r - layer * per;
    int k = rr >> 8, n = rr & 255;
    int kc = k >> 5, kg = (k >> 3) & 3, e = k & 7;
    dst[(size_t)layer * per + (size_t)kc * 8192 + n * 32 + ((kg ^ ((n >> 1) & 3)) << 3) + e]
        = f2bf(src[(size_t)layer * per + rr]);
}

// ---------------- node encoder (scalar fp32, small) ------------------------
__global__ __launch_bounds__(256) void k_encode_nodes(
    const float* __restrict__ nf, const float* __restrict__ W,
    const float* __restrict__ b, float* __restrict__ x, u16* __restrict__ x_bf)
{
    __shared__ float s_nf[4 * 128];
    const int n0 = blockIdx.x * 4;
    const int tid = threadIdx.x;
    reinterpret_cast<float2*>(s_nf)[tid] =
        reinterpret_cast<const float2*>(nf + (size_t)n0 * 128)[tid];
    __syncthreads();
    float acc[4] = {0.f, 0.f, 0.f, 0.f};
    for (int k = 0; k < 128; ++k) {
        float w = W[k * kH + tid];
        #pragma unroll
        for (int r = 0; r < 4; ++r) acc[r] = fmaf(s_nf[r * 128 + k], w, acc[r]);
    }
    float bias = b[tid];
    #pragma unroll
    for (int r = 0; r < 4; ++r) {
        float o = acc[r] + bias;
        x[(size_t)(n0 + r) * kH + tid] = o;
        x_bf[(size_t)(n0 + r) * kH + tid] = f2bf(o);
    }
}

// ---------------- LDS fragment readers (XOR-swizzled) ----------------------
__device__ __forceinline__ bf16x8 rdfrag(const char* lds, int n, int kg) {
    return *reinterpret_cast<const bf16x8*>(lds + n * 64 + ((kg ^ ((n >> 1) & 3)) << 4));
}
__device__ __forceinline__ bf16x8 rdH(const char* H, int row, int kbyte) {
    return *reinterpret_cast<const bf16x8*>(H + row * 512 + (kbyte ^ ((row & 7) << 4)));
}

// ---------------- edge encoder: ea = ef @ eW + b (MFMA, K=64) --------------
__global__ __launch_bounds__(256) void k_enc_e(
    const float* __restrict__ ef, const u16* __restrict__ Wte,
    const float* __restrict__ b, u16* __restrict__ ea_bf)
{
    __shared__ char sW[2][16384];
    __shared__ char sA[2][4096];
    const int tid = threadIdx.x;
    const int e0 = blockIdx.x * 64;
    const int w = tid >> 6, lane = tid & 63;
    const int lr = lane & 15, lg = lane >> 4;
    const int srow = tid >> 2, skg = tid & 3;

    dma_w16k(Wte, sW[0], tid);
    dma_w16k(Wte + 8192, sW[1], tid);
    #pragma unroll
    for (int c = 0; c < 2; ++c) {
        const float* ap = ef + (size_t)(e0 + srow) * 64 + c * 32 + skg * 8;
        F4 a0 = ldF4(ap), a1 = ldF4(ap + 4);
        int4 bv;
        bv.x = (int)f2bf(a0.v[0]) | ((int)f2bf(a0.v[1]) << 16);
        bv.y = (int)f2bf(a0.v[2]) | ((int)f2bf(a0.v[3]) << 16);
        bv.z = (int)f2bf(a1.v[0]) | ((int)f2bf(a1.v[1]) << 16);
        bv.w = (int)f2bf(a1.v[2]) | ((int)f2bf(a1.v[3]) << 16);
        *reinterpret_cast<int4*>(sA[c] + srow * 64 + ((skg ^ ((srow >> 1) & 3)) << 4)) = bv;
    }
    __syncthreads();

    f32x4 acc[4][4];
    #pragma unroll
    for (int i = 0; i < 4; ++i)
        #pragma unroll
        for (int j = 0; j < 4; ++j) acc[i][j] = (f32x4){0.f, 0.f, 0.f, 0.f};
    #pragma unroll
    for (int c = 0; c < 2; ++c) {
        bf16x8 af[4], bfm[4];
        #pragma unroll
        for (int i = 0; i < 4; ++i) af[i] = rdfrag(sW[c], w * 64 + i * 16 + lr, lg);
        #pragma unroll
        for (int j = 0; j < 4; ++j) bfm[j] = rdfrag(sA[c], j * 16 + lr, lg);
        #pragma unroll
        for (int i = 0; i < 4; ++i)
            #pragma unroll
            for (int j = 0; j < 4; ++j)
                acc[i][j] = __builtin_amdgcn_mfma_f32_16x16x32_bf16(af[i], bfm[j], acc[i][j], 0, 0, 0);
    }
    #pragma unroll
    for (int i = 0; i < 4; ++i) {
        const int hc0 = w * 64 + i * 16 + lg * 4;
        const F4 bb = ldF4(b + hc0);
        #pragma unroll
        for (int j = 0; j < 4; ++j) {
            s16x4 o;
            #pragma unroll
            for (int q = 0; q < 4; ++q) o[q] = (short)f2bf(acc[i][j][q] + bb.v[q]);
            *reinterpret_cast<s16x4*>(ea_bf + (size_t)(e0 + j * 16 + lr) * kH + hc0) = o;
        }
    }
}

// ---------------- edge message MLP + segmented scatter ---------------------
// 128-edge tile, 512 threads (8 waves: eh = edge half, wq = hcol quarter).
// T3-min 2-phase: stage(next) -> ds_read+MFMA(cur) -> one __syncthreads.
__global__ __launch_bounds__(512, 2) void k_msg(
    const u16* __restrict__ x_bf, const u16* __restrict__ ea_bf,
    const int* __restrict__ ssorted, const int* __restrict__ dsorted,
    const int* __restrict__ perm,
    const u16* __restrict__ Wt1, const float* __restrict__ b1,
    const u16* __restrict__ Wt2, const float* __restrict__ b2,
    float* __restrict__ agg)
{
    __shared__ char sWt[2][16384];
    __shared__ char sA[2][8192];
    __shared__ char sH[65536];     // h1 / msg dump: [128 edges][256] bf16 swizzled
    __shared__ int sDst[128];

    const int tid = threadIdx.x;
    const int nwg = gridDim.x;
    const int q8 = nwg >> 3, r8 = nwg & 7;
    const int xcd = blockIdx.x & 7, sub = blockIdx.x >> 3;
    const int bid = (xcd < r8 ? xcd * (q8 + 1) : r8 * (q8 + 1) + (xcd - r8) * q8) + sub;
    const int e0 = bid * 128;

    const int w = tid >> 6, lane = tid & 63;
    const int eh = w >> 2, wq = w & 3;
    const int lr = lane & 15, lg = lane >> 4;
    const int srow = tid >> 2, skg = tid & 3;
    const int kg_src = skg ^ ((srow >> 1) & 3);

    const int my_src  = ssorted[e0 + srow];
    const int my_dst  = dsorted[e0 + srow];
    const int my_perm = perm[e0 + srow];
    if (tid < 128) sDst[tid] = dsorted[e0 + tid];

    const u16* gsrc = x_bf + (size_t)my_src * kH + kg_src * 8;
    const u16* gdst = x_bf + (size_t)my_dst * kH + kg_src * 8;
    const u16* gea  = ea_bf + (size_t)my_perm * kH + kg_src * 8;

    auto aptr = [&](int kc) -> const u16* {
        const u16* base = kc < 8 ? gsrc : (kc < 16 ? gdst : gea);
        return base + (kc & 7) * 32;
    };
    auto stage_w = [&](const u16* Wc, char* lds) {     // 16KB over 8 waves
        char* lb = lds + w * 2048;
        const char* gb = (const char*)Wc + w * 2048 + lane * 16;
        gl_lds16(gb, lb);
        gl_lds16(gb + 1024, lb + 1024);
    };
    auto stage_a = [&](const u16* g, char* lds) {      // 8KB over 8 waves
        gl_lds16(g, lds + w * 1024);
    };

    f32x4 acc[4][4];
    #pragma unroll
    for (int i = 0; i < 4; ++i)
        #pragma unroll
        for (int j = 0; j < 4; ++j) acc[i][j] = (f32x4){0.f, 0.f, 0.f, 0.f};

    // prologue
    stage_w(Wt1, sWt[0]);
    stage_a(aptr(0), sA[0]);
    __syncthreads();

    // ---- GEMM1 (swapped): h1^T, K = 768 = 24 chunks ----
    for (int kc = 0; kc < 24; ++kc) {
        const int cur = kc & 1, nxt = cur ^ 1;
        if (kc < 23) {
            stage_w(Wt1 + (size_t)(kc + 1) * 8192, sWt[nxt]);
            stage_a(aptr(kc + 1), sA[nxt]);
        } else {
            stage_w(Wt2, sWt[nxt]);                    // prefetch GEMM2 chunk 0
        }
        bf16x8 af[4], bfm[4];
        #pragma unroll
        for (int i = 0; i < 4; ++i) af[i] = rdfrag(sWt[cur], wq * 64 + i * 16 + lr, lg);
        #pragma unroll
        for (int j = 0; j < 4; ++j) bfm[j] = rdfrag(sA[cur], eh * 64 + j * 16 + lr, lg);
        #pragma unroll
        for (int i = 0; i < 4; ++i)
            #pragma unroll
            for (int j = 0; j < 4; ++j)
                acc[i][j] = __builtin_amdgcn_mfma_f32_16x16x32_bf16(af[i], bfm[j], acc[i][j], 0, 0, 0);
        __syncthreads();
    }

    // ---- epilogue 1: bias + relu -> sH[edge][hcol] ----
    #pragma unroll
    for (int i = 0; i < 4; ++i) {
        const int hc0 = wq * 64 + i * 16 + lg * 4;
        const F4 bb = ldF4(b1 + hc0);
        #pragma unroll
        for (int j = 0; j < 4; ++j) {
            const int edge = eh * 64 + j * 16 + lr;
            s16x4 o;
            #pragma unroll
            for (int q = 0; q < 4; ++q) {
                float h = acc[i][j][q] + bb.v[q];
                h = h > 0.f ? h : 0.f;
                o[q] = (short)f2bf(h);
            }
            int byte = edge * 512 + hc0 * 2;
            *reinterpret_cast<s16x4*>(sH + (byte ^ ((edge & 7) << 4))) = o;
            acc[i][j] = (f32x4){0.f, 0.f, 0.f, 0.f};
        }
    }
    __syncthreads();

    // ---- GEMM2 (normal): msg = h1 @ W2, K = 256 = 8 chunks ----
    // W2 chunk 0 landed in sWt[0] (kc=23: nxt=0)
    for (int kc = 0; kc < 8; ++kc) {
        const int cur = kc & 1, nxt = cur ^ 1;
        if (kc < 7) stage_w(Wt2 + (size_t)(kc + 1) * 8192, sWt[nxt]);
        bf16x8 af2[4], bf2[4];
        #pragma unroll
        for (int i = 0; i < 4; ++i) af2[i] = rdH(sH, eh * 64 + i * 16 + lr, kc * 64 + lg * 16);
        #pragma unroll
        for (int j = 0; j < 4; ++j) bf2[j] = rdfrag(sWt[cur], wq * 64 + j * 16 + lr, lg);
        #pragma unroll
        for (int i = 0; i < 4; ++i)
            #pragma unroll
            for (int j = 0; j < 4; ++j)
                acc[i][j] = __builtin_amdgcn_mfma_f32_16x16x32_bf16(af2[i], bf2[j], acc[i][j], 0, 0, 0);
        __syncthreads();
    }

    // ---- dump msg (bf16) into sH, then segmented reduce by dst ----
    #pragma unroll
    for (int j = 0; j < 4; ++j) {
        const int oc = wq * 64 + j * 16 + lr;
        const float b2v = b2[oc];
        #pragma unroll
        for (int i = 0; i < 4; ++i)
            #pragma unroll
            for (int q = 0; q < 4; ++q) {
                int edge = eh * 64 + i * 16 + lg * 4 + q;
                int byte = edge * 512 + oc * 2;
                *reinterpret_cast<u16*>(sH + (byte ^ ((edge & 7) << 4)))
                    = f2bf(acc[i][j][q] + b2v);
            }
    }
    __syncthreads();

    // per-col serial scan: thread (col, half) scans 64 sorted edges
    {
        const int col = tid & 255;
        const int half = tid >> 8;
        float run = 0.f;
        int prev = sDst[half * 64];
        #pragma unroll 1
        for (int eb = 0; eb < 8; ++eb) {
            float vv[8]; int dd[8];
            #pragma unroll
            for (int t = 0; t < 8; ++t) {
                int e = half * 64 + eb * 8 + t;
                int byte = e * 512 + col * 2;
                vv[t] = bf2f(*reinterpret_cast<const u16*>(sH + (byte ^ ((e & 7) << 4))));
                dd[t] = sDst[e];
            }
            #pragma unroll
            for (int t = 0; t < 8; ++t) {
                if (dd[t] != prev) {
                    unsafeAtomicAdd(agg + (size_t)prev * kH + col, run);
                    run = 0.f; prev = dd[t];
                }
                run += vv[t];
            }
        }
        unsafeAtomicAdd(agg + (size_t)prev * kH + col, run);
    }
}

// ---------------- node update MLP + residual + LayerNorm -------------------
__global__ __launch_bounds__(256, 2) void k_upd(
    float* __restrict__ x, u16* __restrict__ x_bf,
    float* __restrict__ agg,
    const u16* __restrict__ Wt1, const float* __restrict__ b1,
    const u16* __restrict__ Wt2, const float* __restrict__ b2,
    const float* __restrict__ lng, const float* __restrict__ lnb)
{
    __shared__ char sWt[2][16384];
    __shared__ char sA[2][4096];
    __shared__ char sH[32768];

    const int tid = threadIdx.x;
    const int n0 = blockIdx.x * 64;
    const int w = tid >> 6, lane = tid & 63;
    const int lr = lane & 15, lg = lane >> 4;
    const int srow = tid >> 2, skg = tid & 3;
    const int kg_src = skg ^ ((srow >> 1) & 3);
    int gnode = n0 + srow; if (gnode >= kN) gnode = kN - 1;

    dma_w16k(Wt1, sWt[0], tid);
    gl_lds16(x_bf + (size_t)gnode * kH + kg_src * 8, sA[0] + w * 1024);

    f32x4 acc[4][4];
    #pragma unroll
    for (int i = 0; i < 4; ++i)
        #pragma unroll
        for (int j = 0; j < 4; ++j) acc[i][j] = (f32x4){0.f, 0.f, 0.f, 0.f};
    __syncthreads();

    for (int kc = 0; kc < 16; ++kc) {
        const int cur = kc & 1, nxt = cur ^ 1;
        bool do_agg = false; F4 a0, a1;
        if (kc < 15) {
            dma_w16k(Wt1 + (size_t)(kc + 1) * 8192, sWt[nxt], tid);
            if (kc + 1 < 8) {
                gl_lds16(x_bf + (size_t)gnode * kH + (kc + 1) * 32 + kg_src * 8,
                         sA[nxt] + w * 1024);
            } else {
                const float* ap = agg + (size_t)gnode * kH + (kc + 1 - 8) * 32 + skg * 8;
                a0 = ldF4(ap); a1 = ldF4(ap + 4); do_agg = true;
            }
        } else {
            dma_w16k(Wt2, sWt[nxt], tid);
        }
        bf16x8 af[4], bfm[4];
        #pragma unroll
        for (int i = 0; i < 4; ++i) af[i] = rdfrag(sWt[cur], w * 64 + i * 16 + lr, lg);
        #pragma unroll
        for (int j = 0; j < 4; ++j) bfm[j] = rdfrag(sA[cur], j * 16 + lr, lg);
        #pragma unroll
        for (int i = 0; i < 4; ++i)
            #pragma unroll
            for (int j = 0; j < 4; ++j)
                acc[i][j] = __builtin_amdgcn_mfma_f32_16x16x32_bf16(af[i], bfm[j], acc[i][j], 0, 0, 0);
        if (do_agg) {
            int4 bv;
            bv.x = (int)f2bf(a0.v[0]) | ((int)f2bf(a0.v[1]) << 16);
            bv.y = (int)f2bf(a0.v[2]) | ((int)f2bf(a0.v[3]) << 16);
            bv.z = (int)f2bf(a1.v[0]) | ((int)f2bf(a1.v[1]) << 16);
            bv.w = (int)f2bf(a1.v[2]) | ((int)f2bf(a1.v[3]) << 16);
            *reinterpret_cast<int4*>(sA[nxt] + srow * 64 + ((skg ^ ((srow >> 1) & 3)) << 4)) = bv;
        }
        __syncthreads();
    }

    #pragma unroll
    for (int i = 0; i < 4; ++i) {
        const int hc0 = w * 64 + i * 16 + lg * 4;
        const F4 bb = ldF4(b1 + hc0);
        #pragma unroll
        for (int j = 0; j < 4; ++j) {
            const int row = j * 16 + lr;
            s16x4 o;
            #pragma unroll
            for (int q = 0; q < 4; ++q) {
                float h = acc[i][j][q] + bb.v[q];
                h = h > 0.f ? h : 0.f;
                o[q] = (short)f2bf(h);
            }
            int byte = row * 512 + hc0 * 2;
            *reinterpret_cast<s16x4*>(sH + (byte ^ ((row & 7) << 4))) = o;
            acc[i][j] = (f32x4){0.f, 0.f, 0.f, 0.f};
        }
    }
    __syncthreads();

    // zero this block's agg rows for the next layer (replaces memset launches)
    {
        float4 z = make_float4(0.f, 0.f, 0.f, 0.f);
        float4* bp = reinterpret_cast<float4*>(agg + (size_t)n0 * kH);
        #pragma unroll
        for (int i = 0; i < 16; ++i) {
            int idx = i * 256 + tid;        // float4 index within [64][64]
            int row = idx >> 6;
            if (n0 + row < kN) bp[idx] = z;
        }
    }

    for (int kc = 0; kc < 8; ++kc) {
        const int cur = kc & 1, nxt = cur ^ 1;
        if (kc < 7) dma_w16k(Wt2 + (size_t)(kc + 1) * 8192, sWt[nxt], tid);
        bf16x8 af2[4], bf2[4];
        #pragma unroll
        for (int i = 0; i < 4; ++i) af2[i] = rdH(sH, i * 16 + lr, kc * 64 + lg * 16);
        #pragma unroll
        for (int j = 0; j < 4; ++j) bf2[j] = rdfrag(sWt[cur], w * 64 + j * 16 + lr, lg);
        #pragma unroll
        for (int i = 0; i < 4; ++i)
            #pragma unroll
            for (int j = 0; j < 4; ++j)
                acc[i][j] = __builtin_amdgcn_mfma_f32_16x16x32_bf16(af2[i], bf2[j], acc[i][j], 0, 0, 0);
        __syncthreads();
    }

    float b2v[4], gv[4], bvn[4];
    #pragma unroll
    for (int j = 0; j < 4; ++j) {
        int oc = w * 64 + j * 16 + lr;
        b2v[j] = b2[oc]; gv[j] = lng[oc]; bvn[j] = lnb[oc];
    }
    #pragma unroll
    for (int i = 0; i < 4; ++i)
        #pragma unroll
        for (int j = 0; j < 4; ++j) {
            int oc = w * 64 + j * 16 + lr;
            #pragma unroll
            for (int q = 0; q < 4; ++q) {
                int node = n0 + i * 16 + lg * 4 + q;
                int ncl = node < kN ? node : kN - 1;
                acc[i][j][q] += b2v[j] + x[(size_t)ncl * kH + oc];
            }
        }

    float (*red)[64][2] = reinterpret_cast<float(*)[64][2]>(sA[0]);
    float2* mstd = reinterpret_cast<float2*>(sA[0] + 2048);
    __syncthreads();
    #pragma unroll
    for (int i = 0; i < 4; ++i)
        #pragma unroll
        for (int q = 0; q < 4; ++q) {
            float s = acc[i][0][q] + acc[i][1][q] + acc[i][2][q] + acc[i][3][q];
            float ss = acc[i][0][q] * acc[i][0][q] + acc[i][1][q] * acc[i][1][q]
                     + acc[i][2][q] * acc[i][2][q] + acc[i][3][q] * acc[i][3][q];
            #pragma unroll
            for (int m = 1; m < 16; m <<= 1) { s += __shfl_xor(s, m); ss += __shfl_xor(ss, m); }
            if (lr == 0) { red[w][i * 16 + lg * 4 + q][0] = s; red[w][i * 16 + lg * 4 + q][1] = ss; }
        }
    __syncthreads();
    if (tid < 64) {
        float s = red[0][tid][0] + red[1][tid][0] + red[2][tid][0] + red[3][tid][0];
        float ss = red[0][tid][1] + red[1][tid][1] + red[2][tid][1] + red[3][tid][1];
        float mean = s * (1.f / 256.f);
        float var = ss * (1.f / 256.f) - mean * mean;
        mstd[tid] = make_float2(mean, rsqrtf(var + kEps));
    }
    __syncthreads();
    #pragma unroll
    for (int i = 0; i < 4; ++i)
        #pragma unroll
        for (int j = 0; j < 4; ++j) {
            int oc = w * 64 + j * 16 + lr;
            #pragma unroll
            for (int q = 0; q < 4; ++q) {
                int nn = i * 16 + lg * 4 + q;
                int node = n0 + nn;
                if (node < kN) {
                    float2 ms = mstd[nn];
                    float o = (acc[i][j][q] - ms.x) * ms.y * gv[j] + bvn[j];
                    x[(size_t)node * kH + oc] = o;
                    x_bf[(size_t)node * kH + oc] = f2bf(o);
                }
            }
        }
}

// ---------------- fused pooling + readout ----------------------------------
__device__ __forceinline__ int lower_bound_i(const int* a, int n, int v) {
    int lo = 0, hi = n;
    while (lo < hi) { int m = (lo + hi) >> 1; if (a[m] < v) lo = m + 1; else hi = m; }
    return lo;
}

__global__ __launch_bounds__(256) void k_pool_ro(
    const float* __restrict__ x, const int* __restrict__ batch,
    const float* __restrict__ W1, const float* __restrict__ b1,
    const float* __restrict__ W2, const float* __restrict__ b2,
    float* __restrict__ out)
{
    __shared__ float ph[kH];
    __shared__ float h1[kH];
    const int b = blockIdx.x, t = threadIdx.x;
    const int s = lower_bound_i(batch, kN, b);
    const int e = lower_bound_i(batch, kN, b + 1);
    float acc = 0.f;
    for (int i = s; i < e; ++i) acc += x[(size_t)i * kH + t];
    ph[t] = acc / (float)(e - s);
    __syncthreads();
    float a = b1[t];
    for (int k = 0; k < kH; ++k) a = fmaf(ph[k], W1[k * kH + t], a);
    h1[t] = a > 0.f ? a : 0.f;
    __syncthreads();
    if (t < kC) {
        float o = b2[t];
        for (int k = 0; k < kH; ++k) o = fmaf(h1[k], W2[k * kC + t], o);
        out[b * kC + t] = o;
    }
}

// ---------------- launch ---------------------------------------------------
extern "C" void kernel_launch(void* const* d_in, const int* in_sizes, int n_in,
                              void* d_out, int out_size, void* d_ws, size_t ws_size,
                              hipStream_t stream)
{
    const float* nf     = (const float*)d_in[0];
    const void*  ei_raw = d_in[1];
    const float* ef     = (const float*)d_in[2];
    const void*  ba_raw = d_in[3];
    const float* node_W = (const float*)d_in[4];
    const float* node_b = (const float*)d_in[5];
    const float* edge_W = (const float*)d_in[6];
    const float* edge_b = (const float*)d_in[7];
    const float* msg_W1 = (const float*)d_in[8];
    const float* msg_b1 = (const float*)d_in[9];
    const float* msg_W2 = (const float*)d_in[10];
    const float* msg_b2 = (const float*)d_in[11];
    const float* upd_W1 = (const float*)d_in[12];
    const float* upd_b1 = (const float*)d_in[13];
    const float* upd_W2 = (const float*)d_in[14];
    const float* upd_b2 = (const float*)d_in[15];
    const float* ln_g   = (const float*)d_in[16];
    const float* ln_b   = (const float*)d_in[17];
    const float* ro_W1  = (const float*)d_in[18];
    const float* ro_b1  = (const float*)d_in[19];
    const float* ro_W2  = (const float*)d_in[20];
    const float* ro_b2  = (const float*)d_in[21];

    char* p = (char*)d_ws;
    auto alloc = [&](size_t bytes) { char* r = p; p += (bytes + 255) & ~(size_t)255; return r; };
    float* x      = (float*)alloc((size_t)kN * kH * 4);
    float* agg    = (float*)alloc((size_t)kN * kH * 4);
    u16* x_bf  = (u16*)alloc((size_t)kN * kH * 2);
    u16* ea_bf = (u16*)alloc((size_t)kE * kH * 2);
    u16* tm1 = (u16*)alloc((size_t)kL * 768 * 256 * 2);
    u16* tm2 = (u16*)alloc((size_t)kL * 256 * 256 * 2);
    u16* tu1 = (u16*)alloc((size_t)kL * 512 * 256 * 2);
    u16* tu2 = (u16*)alloc((size_t)kL * 256 * 256 * 2);
    u16* te  = (u16*)alloc((size_t)64 * 256 * 2);
    int* ei32 = (int*)alloc((size_t)2 * kE * 4);
    int* ba32 = (int*)alloc((size_t)kN * 4);
    int* cnt  = (int*)alloc((size_t)kN * 4);
    int* cur  = (int*)alloc((size_t)kN * 4);
    int* perm = (int*)alloc((size_t)kE * 4);
    int* ssorted = (int*)alloc((size_t)kE * 4);
    int* dsorted = (int*)alloc((size_t)kE * 4);
    int* flag = (int*)alloc(4);

    k_detect_i64<<<1, 64, 0, stream>>>((const unsigned*)ei_raw, flag);
    k_cvt_idx<<<(2 * kE + 255) / 256, 256, 0, stream>>>((const unsigned*)ei_raw, flag, ei32, 2 * kE);
    k_cvt_idx<<<(kN + 255) / 256, 256, 0, stream>>>((const unsigned*)ba_raw, flag, ba32, kN);
    const int* src = ei32;
    const int* dst = ei32 + kE;

    hipMemsetAsync(cnt, 0, (size_t)kN * 4, stream);
    k_hist<<<(kE + 255) / 256, 256, 0, stream>>>(dst, cnt);
    k_scan<<<1, 256, 0, stream>>>(cnt, cur);
    k_scatter<<<(kE + 255) / 256, 256, 0, stream>>>(src, dst, cur, perm, ssorted, dsorted);

    const int prep_elems = kL * (768 + 256 + 512 + 256) * 256 + 64 * 256;
    k_prep_w<<<(prep_elems + 255) / 256, 256, 0, stream>>>(
        msg_W1, msg_W2, upd_W1, upd_W2, edge_W, tm1, tm2, tu1, tu2, te);

    k_encode_nodes<<<kN / 4, 256, 0, stream>>>(nf, node_W, node_b, x, x_bf);
    k_enc_e<<<kE / 64, 256, 0, stream>>>(ef, te, edge_b, ea_bf);

    hipMemsetAsync(agg, 0, (size_t)kN * kH * sizeof(float), stream);
    for (int l = 0; l < kL; ++l) {
        k_msg<<<kE / 128, 512, 0, stream>>>(x_bf, ea_bf, ssorted, dsorted, perm,
            tm1 + (size_t)l * 768 * 256, msg_b1 + l * kH,
            tm2 + (size_t)l * 256 * 256, msg_b2 + l * kH, agg);
        k_upd<<<(kN + 63) / 64, 256, 0, stream>>>(x, x_bf, agg,
            tu1 + (size_t)l * 512 * 256, upd_b1 + l * kH,
            tu2 + (size_t)l * 256 * 256, upd_b2 + l * kH,
            ln_g + l * kH, ln_b + l * kH);
    }

    k_pool_ro<<<kB, 256, 0, stream>>>(x, ba32, ro_W1, ro_b1, ro_W2, ro_b2, (float*)d_out);
}

// Round 6
// 608.731 us; speedup vs baseline: 1.4639x; 1.4639x over previous
//
#include <hip/hip_runtime.h>
#include <cstdint>
#include <cstddef>

// ---------------------------------------------------------------------------
// GraphMathSolver: 4-layer MPNN on MI355X.
// Round 6: algebraic dedupe.
//   h1 = relu( y_a[src] + y_b[dst] + ef@M[l] + b1'[l] )
//     y_a = x@W1a, y_b = x@W1b   (per-NODE, computed once per layer)
//     M[l] = We@W1c[l], b1' = b1 + be@W1c[l]  (edge encoder is linear!)
//   -> k_msg GEMM1 K: 768 -> 64; ea_bf buffer + k_enc_e eliminated.
//   k_msg back to round-4 shape (256 thr, 53.5KB LDS, 3 blocks/CU);
//   ysum staged into sH (same element ownership as h1 -> buffer reuse).
// ---------------------------------------------------------------------------

typedef unsigned short u16;
typedef __attribute__((ext_vector_type(4))) float f32x4;
typedef __attribute__((ext_vector_type(8))) short bf16x8;
typedef __attribute__((ext_vector_type(4))) short s16x4;

constexpr int kN  = 10000;
constexpr int kE  = 160000;
constexpr int kB  = 64;
constexpr int kH  = 256;
constexpr int kL  = 4;
constexpr int kC  = 10;
constexpr float kEps = 1e-5f;

struct __align__(16) F4 { float v[4]; };
__device__ __forceinline__ F4 ldF4(const float* p) { return *reinterpret_cast<const F4*>(p); }

__device__ __forceinline__ u16 f2bf(float f) {
    unsigned u = __builtin_bit_cast(unsigned, f);
    return (u16)((u + 0x7fffu + ((u >> 16) & 1u)) >> 16);
}
__device__ __forceinline__ float bf2f(u16 h) {
    return __builtin_bit_cast(float, (unsigned)h << 16);
}

// ---- async global->LDS DMA, 16B per lane ----------------------------------
typedef __attribute__((address_space(1))) void GV;
typedef __attribute__((address_space(3))) void LV;
__device__ __forceinline__ void gl_lds16(const void* g, void* l) {
    __builtin_amdgcn_global_load_lds((GV*)g, (LV*)l, 16, 0, 0);
}
__device__ __forceinline__ void dma_w16k(const u16* __restrict__ Wc, char* lds, int tid) {
    const int w = tid >> 6, lane = tid & 63;
    char* lb = lds + w * 4096;
    const char* gb = (const char*)Wc + w * 4096 + lane * 16;
    #pragma unroll
    for (int i = 0; i < 4; ++i) gl_lds16(gb + i * 1024, lb + i * 1024);
}

// ---------------- int64/int32 index handling -------------------------------
__global__ void k_detect_i64(const unsigned* __restrict__ w, int* __restrict__ flag) {
    if (threadIdx.x == 0 && blockIdx.x == 0) {
        int is64 = 1;
        for (int i = 0; i < 64; ++i)
            if (w[2*i + 1] != 0u) { is64 = 0; break; }
        *flag = is64;
    }
}
__global__ void k_cvt_idx(const unsigned* __restrict__ w, const int* __restrict__ flag,
                          int* __restrict__ out, int n) {
    int i = blockIdx.x * 256 + threadIdx.x;
    if (i < n) out[i] = (*flag) ? (int)w[2*i] : (int)w[i];
}

// ---------------- counting sort of edges by dst ----------------------------
__global__ __launch_bounds__(256) void k_hist(const int* __restrict__ dst,
                                              int* __restrict__ cnt) {
    int e = blockIdx.x * 256 + threadIdx.x;
    if (e < kE) atomicAdd(&cnt[dst[e]], 1);
}
__global__ __launch_bounds__(256) void k_scan(const int* __restrict__ cnt,
                                              int* __restrict__ cur) {
    __shared__ int part[256];
    const int t = threadIdx.x;
    const int per = (kN + 255) / 256;
    int s = 0;
    for (int i = 0; i < per; ++i) {
        int idx = t * per + i;
        if (idx < kN) s += cnt[idx];
    }
    int own = s;
    part[t] = s; __syncthreads();
    for (int off = 1; off < 256; off <<= 1) {
        int v = (t >= off) ? part[t - off] : 0;
        __syncthreads();
        part[t] += v;
        __syncthreads();
    }
    int run = part[t] - own;
    for (int i = 0; i < per; ++i) {
        int idx = t * per + i;
        if (idx < kN) { cur[idx] = run; run += cnt[idx]; }
    }
}
__global__ __launch_bounds__(256) void k_scatter(
    const int* __restrict__ src, const int* __restrict__ dst,
    int* __restrict__ cur, int* __restrict__ perm,
    int* __restrict__ ssorted, int* __restrict__ dsorted) {
    int e = blockIdx.x * 256 + threadIdx.x;
    if (e < kE) {
        int d = dst[e];
        int p = atomicAdd(&cur[d], 1);
        perm[p] = e;
        ssorted[p] = src[e];
        dsorted[p] = d;
    }
}

// ---- weight prep: fp32 [L][K][256] -> bf16 swizzled-linear [L][kc][n][32] --
__global__ __launch_bounds__(256) void k_prep_w(
    const float* __restrict__ mW1, const float* __restrict__ mW2,
    const float* __restrict__ uW1, const float* __restrict__ uW2,
    u16* __restrict__ tm1, u16* __restrict__ tm2,
    u16* __restrict__ tu1, u16* __restrict__ tu2)
{
    int idx = blockIdx.x * 256 + threadIdx.x;
    const int S1 = kL * 768 * 256;
    const int S2 = S1 + kL * 256 * 256;
    const int S3 = S2 + kL * 512 * 256;
    const int S4 = S3 + kL * 256 * 256;
    const float* src; u16* dst; int K, r;
    if (idx < S1)      { src = mW1; dst = tm1; K = 768; r = idx; }
    else if (idx < S2) { src = mW2; dst = tm2; K = 256; r = idx - S1; }
    else if (idx < S3) { src = uW1; dst = tu1; K = 512; r = idx - S2; }
    else if (idx < S4) { src = uW2; dst = tu2; K = 256; r = idx - S3; }
    else return;
    int per = K * 256;
    int layer = r / per, rr = r - layer * per;
    int k = rr >> 8, n = rr & 255;
    int kc = k >> 5, kg = (k >> 3) & 3, e = k & 7;
    dst[(size_t)layer * per + (size_t)kc * 8192 + n * 32 + ((kg ^ ((n >> 1) & 3)) << 3) + e]
        = f2bf(src[(size_t)layer * per + rr]);
}

// ---- M[l] = We @ W1c[l] (64x256), b1'[l] = b1[l] + be @ W1c[l] -------------
// grid (L, 4): blockIdx.y picks 16 rows of M. Output in k-chunk swizzled bf16.
__global__ __launch_bounds__(256) void k_prep_m(
    const float* __restrict__ eW, const float* __restrict__ eb,
    const float* __restrict__ mW1, const float* __restrict__ mb1,
    u16* __restrict__ tmc, float* __restrict__ b1p)
{
    __shared__ float sWe[16 * 256];
    const int l = blockIdx.x, rq = blockIdx.y, t = threadIdx.x;
    const int r0 = rq * 16;
    #pragma unroll
    for (int i = 0; i < 16; ++i) sWe[i * 256 + t] = eW[(size_t)(r0 + i) * 256 + t];
    __syncthreads();
    const float* W1c = mW1 + (size_t)l * 768 * 256 + (size_t)512 * 256;
    float m[16];
    #pragma unroll
    for (int r = 0; r < 16; ++r) m[r] = 0.f;
    float bp = (rq == 0) ? mb1[l * 256 + t] : 0.f;
    for (int j = 0; j < 256; ++j) {
        float wv = W1c[(size_t)j * 256 + t];
        if (rq == 0) bp = fmaf(eb[j], wv, bp);
        #pragma unroll
        for (int r = 0; r < 16; ++r) m[r] = fmaf(sWe[r * 256 + j], wv, m[r]);
    }
    if (rq == 0) b1p[l * 256 + t] = bp;
    #pragma unroll
    for (int r = 0; r < 16; ++r) {
        int k = r0 + r;
        int kc = k >> 5, kg = (k >> 3) & 3, e = k & 7;
        tmc[(size_t)l * 16384 + (size_t)kc * 8192 + t * 32
            + ((kg ^ ((t >> 1) & 3)) << 3) + e] = f2bf(m[r]);
    }
}

// ---------------- node encoder (scalar fp32, small) ------------------------
__global__ __launch_bounds__(256) void k_encode_nodes(
    const float* __restrict__ nf, const float* __restrict__ W,
    const float* __restrict__ b, float* __restrict__ x, u16* __restrict__ x_bf)
{
    __shared__ float s_nf[4 * 128];
    const int n0 = blockIdx.x * 4;
    const int tid = threadIdx.x;
    reinterpret_cast<float2*>(s_nf)[tid] =
        reinterpret_cast<const float2*>(nf + (size_t)n0 * 128)[tid];
    __syncthreads();
    float acc[4] = {0.f, 0.f, 0.f, 0.f};
    for (int k = 0; k < 128; ++k) {
        float w = W[k * kH + tid];
        #pragma unroll
        for (int r = 0; r < 4; ++r) acc[r] = fmaf(s_nf[r * 128 + k], w, acc[r]);
    }
    float bias = b[tid];
    #pragma unroll
    for (int r = 0; r < 4; ++r) {
        float o = acc[r] + bias;
        x[(size_t)(n0 + r) * kH + tid] = o;
        x_bf[(size_t)(n0 + r) * kH + tid] = f2bf(o);
    }
}

// ---------------- LDS fragment readers (XOR-swizzled) ----------------------
__device__ __forceinline__ bf16x8 rdfrag(const char* lds, int n, int kg) {
    return *reinterpret_cast<const bf16x8*>(lds + n * 64 + ((kg ^ ((n >> 1) & 3)) << 4));
}
__device__ __forceinline__ bf16x8 rdH(const char* H, int row, int kbyte) {
    return *reinterpret_cast<const bf16x8*>(H + row * 512 + (kbyte ^ ((row & 7) << 4)));
}

// ---------------- per-node pre-GEMM: y = x @ W1half (K=256) ----------------
__global__ __launch_bounds__(256, 3) void k_node_pre(
    const u16* __restrict__ x_bf, const u16* __restrict__ Wt1,
    u16* __restrict__ y_a, u16* __restrict__ y_b)
{
    __shared__ char sWt[16384];
    __shared__ char sA[4096];
    const int tid = threadIdx.x;
    const int n0 = blockIdx.x * 64;
    const int half = blockIdx.y;
    const u16* Wt = Wt1 + (size_t)half * 8 * 8192;
    u16* y = half ? y_b : y_a;
    const int w = tid >> 6, lane = tid & 63;
    const int lr = lane & 15, lg = lane >> 4;
    const int srow = tid >> 2, skg = tid & 3;
    const int kg_src = skg ^ ((srow >> 1) & 3);
    int gnode = n0 + srow; if (gnode >= kN) gnode = kN - 1;

    f32x4 acc[4][4];
    #pragma unroll
    for (int i = 0; i < 4; ++i)
        #pragma unroll
        for (int j = 0; j < 4; ++j) acc[i][j] = (f32x4){0.f, 0.f, 0.f, 0.f};

    for (int kc = 0; kc < 8; ++kc) {
        __syncthreads();
        dma_w16k(Wt + (size_t)kc * 8192, sWt, tid);
        gl_lds16(x_bf + (size_t)gnode * kH + kc * 32 + kg_src * 8, sA + w * 1024);
        __syncthreads();
        bf16x8 af[4], bfm[4];
        #pragma unroll
        for (int i = 0; i < 4; ++i) af[i] = rdfrag(sWt, w * 64 + i * 16 + lr, lg);
        #pragma unroll
        for (int j = 0; j < 4; ++j) bfm[j] = rdfrag(sA, j * 16 + lr, lg);
        #pragma unroll
        for (int i = 0; i < 4; ++i)
            #pragma unroll
            for (int j = 0; j < 4; ++j)
                acc[i][j] = __builtin_amdgcn_mfma_f32_16x16x32_bf16(af[i], bfm[j], acc[i][j], 0, 0, 0);
    }
    #pragma unroll
    for (int i = 0; i < 4; ++i) {
        const int hc0 = w * 64 + i * 16 + lg * 4;
        #pragma unroll
        for (int j = 0; j < 4; ++j) {
            const int node = n0 + j * 16 + lr;
            if (node < kN) {
                s16x4 o;
                #pragma unroll
                for (int q = 0; q < 4; ++q) o[q] = (short)f2bf(acc[i][j][q]);
                *reinterpret_cast<s16x4*>(y + (size_t)node * kH + hc0) = o;
            }
        }
    }
}

// ---------------- edge message MLP + segmented scatter ---------------------
// h1 = relu(ysum + ef@M + b1'); msg = h1@W2. 53.5KB LDS -> 3 blocks/CU.
__global__ __launch_bounds__(256, 3) void k_msg(
    const float* __restrict__ ef,
    const int* __restrict__ ssorted, const int* __restrict__ dsorted,
    const int* __restrict__ perm,
    const u16* __restrict__ y_a, const u16* __restrict__ y_b,
    const u16* __restrict__ Wtm, const float* __restrict__ b1p,
    const u16* __restrict__ Wt2, const float* __restrict__ b2,
    float* __restrict__ agg)
{
    __shared__ char sWt[16384];   // weight chunk
    __shared__ char sA[4096];     // ef chunk (bf16)
    __shared__ char sH[32768];    // ysum -> h1 -> msg dump ([64][256] bf16 swz)
    __shared__ int sDst[64];

    const int tid = threadIdx.x;
    const int nwg = gridDim.x;
    const int q8 = nwg >> 3, r8 = nwg & 7;
    const int xcd = blockIdx.x & 7, sub = blockIdx.x >> 3;
    const int bid = (xcd < r8 ? xcd * (q8 + 1) : r8 * (q8 + 1) + (xcd - r8) * q8) + sub;
    const int e0 = bid * 64;

    const int w = tid >> 6, lane = tid & 63;
    const int lr = lane & 15, lg = lane >> 4;
    const int srow = tid >> 2, skg = tid & 3;

    const int my_src  = ssorted[e0 + srow];
    const int my_dst  = dsorted[e0 + srow];
    const int my_perm = perm[e0 + srow];
    if (tid < 64) sDst[tid] = dsorted[e0 + tid];

    // ---- stage ysum = y_a[src] + y_b[dst] into sH (bf16, swizzled) ----
    #pragma unroll
    for (int m = 0; m < 8; ++m) {
        int col0 = skg * 8 + m * 32;
        bf16x8 va = *reinterpret_cast<const bf16x8*>(y_a + (size_t)my_src * kH + col0);
        bf16x8 vb = *reinterpret_cast<const bf16x8*>(y_b + (size_t)my_dst * kH + col0);
        bf16x8 o;
        #pragma unroll
        for (int t = 0; t < 8; ++t)
            o[t] = (short)f2bf(bf2f((u16)va[t]) + bf2f((u16)vb[t]));
        int byte = srow * 512 + col0 * 2;
        *reinterpret_cast<bf16x8*>(sH + (byte ^ ((srow & 7) << 4))) = o;
    }

    f32x4 acc[4][4];
    #pragma unroll
    for (int i = 0; i < 4; ++i)
        #pragma unroll
        for (int j = 0; j < 4; ++j) acc[i][j] = (f32x4){0.f, 0.f, 0.f, 0.f};

    // ---- GEMM1 (swapped): pe^T = M^T @ ef^T, K = 64 = 2 chunks ----
    for (int kc = 0; kc < 2; ++kc) {
        __syncthreads();
        dma_w16k(Wtm + (size_t)kc * 8192, sWt, tid);
        {   // reg-stage ef chunk (fp32 -> bf16)
            const float* ap = ef + (size_t)my_perm * 64 + kc * 32 + skg * 8;
            F4 a0 = ldF4(ap), a1 = ldF4(ap + 4);
            int4 bv;
            bv.x = (int)f2bf(a0.v[0]) | ((int)f2bf(a0.v[1]) << 16);
            bv.y = (int)f2bf(a0.v[2]) | ((int)f2bf(a0.v[3]) << 16);
            bv.z = (int)f2bf(a1.v[0]) | ((int)f2bf(a1.v[1]) << 16);
            bv.w = (int)f2bf(a1.v[2]) | ((int)f2bf(a1.v[3]) << 16);
            *reinterpret_cast<int4*>(sA + srow * 64 + ((skg ^ ((srow >> 1) & 3)) << 4)) = bv;
        }
        __syncthreads();
        bf16x8 af[4], bfm[4];
        #pragma unroll
        for (int i = 0; i < 4; ++i) af[i] = rdfrag(sWt, w * 64 + i * 16 + lr, lg);
        #pragma unroll
        for (int j = 0; j < 4; ++j) bfm[j] = rdfrag(sA, j * 16 + lr, lg);
        #pragma unroll
        for (int i = 0; i < 4; ++i)
            #pragma unroll
            for (int j = 0; j < 4; ++j)
                acc[i][j] = __builtin_amdgcn_mfma_f32_16x16x32_bf16(af[i], bfm[j], acc[i][j], 0, 0, 0);
    }

    // ---- epilogue 1: h1 = relu(pe + b1' + ysum) -> sH (same slots) ----
    #pragma unroll
    for (int i = 0; i < 4; ++i) {
        const int hc0 = w * 64 + i * 16 + lg * 4;
        const F4 bb = ldF4(b1p + hc0);
        #pragma unroll
        for (int j = 0; j < 4; ++j) {
            const int edge = j * 16 + lr;
            int addr = (edge * 512 + hc0 * 2) ^ ((edge & 7) << 4);
            s16x4 ys = *reinterpret_cast<const s16x4*>(sH + addr);
            s16x4 o;
            #pragma unroll
            for (int q = 0; q < 4; ++q) {
                float h = acc[i][j][q] + bb.v[q] + bf2f((u16)ys[q]);
                h = h > 0.f ? h : 0.f;
                o[q] = (short)f2bf(h);
            }
            *reinterpret_cast<s16x4*>(sH + addr) = o;
            acc[i][j] = (f32x4){0.f, 0.f, 0.f, 0.f};
        }
    }

    // ---- GEMM2 (normal): msg = h1 @ W2, K = 256 = 8 chunks ----
    for (int kc = 0; kc < 8; ++kc) {
        __syncthreads();
        dma_w16k(Wt2 + (size_t)kc * 8192, sWt, tid);
        __syncthreads();
        bf16x8 af2[4], bf2[4];
        #pragma unroll
        for (int i = 0; i < 4; ++i) af2[i] = rdH(sH, i * 16 + lr, kc * 64 + lg * 16);
        #pragma unroll
        for (int j = 0; j < 4; ++j) bf2[j] = rdfrag(sWt, w * 64 + j * 16 + lr, lg);
        #pragma unroll
        for (int i = 0; i < 4; ++i)
            #pragma unroll
            for (int j = 0; j < 4; ++j)
                acc[i][j] = __builtin_amdgcn_mfma_f32_16x16x32_bf16(af2[i], bf2[j], acc[i][j], 0, 0, 0);
    }

    // ---- dump msg (bf16) into sH, then segmented reduce by dst ----
    __syncthreads();
    #pragma unroll
    for (int j = 0; j < 4; ++j) {
        const int oc = w * 64 + j * 16 + lr;
        const float b2v = b2[oc];
        #pragma unroll
        for (int i = 0; i < 4; ++i)
            #pragma unroll
            for (int q = 0; q < 4; ++q) {
                int edge = i * 16 + lg * 4 + q;
                int byte = edge * 512 + oc * 2;
                *reinterpret_cast<u16*>(sH + (byte ^ ((edge & 7) << 4)))
                    = f2bf(acc[i][j][q] + b2v);
            }
    }
    __syncthreads();

    {
        const int col = tid;
        float run = 0.f;
        int prev = sDst[0];
        #pragma unroll 1
        for (int eb = 0; eb < 8; ++eb) {
            float vv[8]; int dd[8];
            #pragma unroll
            for (int t = 0; t < 8; ++t) {
                int e = eb * 8 + t;
                int byte = e * 512 + col * 2;
                vv[t] = bf2f(*reinterpret_cast<const u16*>(sH + (byte ^ ((e & 7) << 4))));
                dd[t] = sDst[e];
            }
            #pragma unroll
            for (int t = 0; t < 8; ++t) {
                if (dd[t] != prev) {
                    unsafeAtomicAdd(agg + (size_t)prev * kH + col, run);
                    run = 0.f; prev = dd[t];
                }
                run += vv[t];
            }
        }
        unsafeAtomicAdd(agg + (size_t)prev * kH + col, run);
    }
}

// ---------------- node update MLP + residual + LayerNorm -------------------
__global__ __launch_bounds__(256, 2) void k_upd(
    float* __restrict__ x, u16* __restrict__ x_bf,
    float* __restrict__ agg,
    const u16* __restrict__ Wt1, const float* __restrict__ b1,
    const u16* __restrict__ Wt2, const float* __restrict__ b2,
    const float* __restrict__ lng, const float* __restrict__ lnb)
{
    __shared__ char sWt[2][16384];
    __shared__ char sA[2][4096];
    __shared__ char sH[32768];

    const int tid = threadIdx.x;
    const int n0 = blockIdx.x * 64;
    const int w = tid >> 6, lane = tid & 63;
    const int lr = lane & 15, lg = lane >> 4;
    const int srow = tid >> 2, skg = tid & 3;
    const int kg_src = skg ^ ((srow >> 1) & 3);
    int gnode = n0 + srow; if (gnode >= kN) gnode = kN - 1;

    dma_w16k(Wt1, sWt[0], tid);
    gl_lds16(x_bf + (size_t)gnode * kH + kg_src * 8, sA[0] + w * 1024);

    f32x4 acc[4][4];
    #pragma unroll
    for (int i = 0; i < 4; ++i)
        #pragma unroll
        for (int j = 0; j < 4; ++j) acc[i][j] = (f32x4){0.f, 0.f, 0.f, 0.f};
    __syncthreads();

    for (int kc = 0; kc < 16; ++kc) {
        const int cur = kc & 1, nxt = cur ^ 1;
        bool do_agg = false; F4 a0, a1;
        if (kc < 15) {
            dma_w16k(Wt1 + (size_t)(kc + 1) * 8192, sWt[nxt], tid);
            if (kc + 1 < 8) {
                gl_lds16(x_bf + (size_t)gnode * kH + (kc + 1) * 32 + kg_src * 8,
                         sA[nxt] + w * 1024);
            } else {
                const float* ap = agg + (size_t)gnode * kH + (kc + 1 - 8) * 32 + skg * 8;
                a0 = ldF4(ap); a1 = ldF4(ap + 4); do_agg = true;
            }
        } else {
            dma_w16k(Wt2, sWt[nxt], tid);
        }
        bf16x8 af[4], bfm[4];
        #pragma unroll
        for (int i = 0; i < 4; ++i) af[i] = rdfrag(sWt[cur], w * 64 + i * 16 + lr, lg);
        #pragma unroll
        for (int j = 0; j < 4; ++j) bfm[j] = rdfrag(sA[cur], j * 16 + lr, lg);
        #pragma unroll
        for (int i = 0; i < 4; ++i)
            #pragma unroll
            for (int j = 0; j < 4; ++j)
                acc[i][j] = __builtin_amdgcn_mfma_f32_16x16x32_bf16(af[i], bfm[j], acc[i][j], 0, 0, 0);
        if (do_agg) {
            int4 bv;
            bv.x = (int)f2bf(a0.v[0]) | ((int)f2bf(a0.v[1]) << 16);
            bv.y = (int)f2bf(a0.v[2]) | ((int)f2bf(a0.v[3]) << 16);
            bv.z = (int)f2bf(a1.v[0]) | ((int)f2bf(a1.v[1]) << 16);
            bv.w = (int)f2bf(a1.v[2]) | ((int)f2bf(a1.v[3]) << 16);
            *reinterpret_cast<int4*>(sA[nxt] + srow * 64 + ((skg ^ ((srow >> 1) & 3)) << 4)) = bv;
        }
        __syncthreads();
    }

    #pragma unroll
    for (int i = 0; i < 4; ++i) {
        const int hc0 = w * 64 + i * 16 + lg * 4;
        const F4 bb = ldF4(b1 + hc0);
        #pragma unroll
        for (int j = 0; j < 4; ++j) {
            const int row = j * 16 + lr;
            s16x4 o;
            #pragma unroll
            for (int q = 0; q < 4; ++q) {
                float h = acc[i][j][q] + bb.v[q];
                h = h > 0.f ? h : 0.f;
                o[q] = (short)f2bf(h);
            }
            int byte = row * 512 + hc0 * 2;
            *reinterpret_cast<s16x4*>(sH + (byte ^ ((row & 7) << 4))) = o;
            acc[i][j] = (f32x4){0.f, 0.f, 0.f, 0.f};
        }
    }
    __syncthreads();

    // zero this block's agg rows for the next layer
    {
        float4 z = make_float4(0.f, 0.f, 0.f, 0.f);
        float4* bp = reinterpret_cast<float4*>(agg + (size_t)n0 * kH);
        #pragma unroll
        for (int i = 0; i < 16; ++i) {
            int idx = i * 256 + tid;
            int row = idx >> 6;
            if (n0 + row < kN) bp[idx] = z;
        }
    }

    for (int kc = 0; kc < 8; ++kc) {
        const int cur = kc & 1, nxt = cur ^ 1;
        if (kc < 7) dma_w16k(Wt2 + (size_t)(kc + 1) * 8192, sWt[nxt], tid);
        bf16x8 af2[4], bf2[4];
        #pragma unroll
        for (int i = 0; i < 4; ++i) af2[i] = rdH(sH, i * 16 + lr, kc * 64 + lg * 16);
        #pragma unroll
        for (int j = 0; j < 4; ++j) bf2[j] = rdfrag(sWt[cur], w * 64 + j * 16 + lr, lg);
        #pragma unroll
        for (int i = 0; i < 4; ++i)
            #pragma unroll
            for (int j = 0; j < 4; ++j)
                acc[i][j] = __builtin_amdgcn_mfma_f32_16x16x32_bf16(af2[i], bf2[j], acc[i][j], 0, 0, 0);
        __syncthreads();
    }

    float b2v[4], gv[4], bvn[4];
    #pragma unroll
    for (int j = 0; j < 4; ++j) {
        int oc = w * 64 + j * 16 + lr;
        b2v[j] = b2[oc]; gv[j] = lng[oc]; bvn[j] = lnb[oc];
    }
    #pragma unroll
    for (int i = 0; i < 4; ++i)
        #pragma unroll
        for (int j = 0; j < 4; ++j) {
            int oc = w * 64 + j * 16 + lr;
            #pragma unroll
            for (int q = 0; q < 4; ++q) {
                int node = n0 + i * 16 + lg * 4 + q;
                int ncl = node < kN ? node : kN - 1;
                acc[i][j][q] += b2v[j] + x[(size_t)ncl * kH + oc];
            }
        }

    float (*red)[64][2] = reinterpret_cast<float(*)[64][2]>(sA[0]);
    float2* mstd = reinterpret_cast<float2*>(sA[0] + 2048);
    __syncthreads();
    #pragma unroll
    for (int i = 0; i < 4; ++i)
        #pragma unroll
        for (int q = 0; q < 4; ++q) {
            float s = acc[i][0][q] + acc[i][1][q] + acc[i][2][q] + acc[i][3][q];
            float ss = acc[i][0][q] * acc[i][0][q] + acc[i][1][q] * acc[i][1][q]
                     + acc[i][2][q] * acc[i][2][q] + acc[i][3][q] * acc[i][3][q];
            #pragma unroll
            for (int m = 1; m < 16; m <<= 1) { s += __shfl_xor(s, m); ss += __shfl_xor(ss, m); }
            if (lr == 0) { red[w][i * 16 + lg * 4 + q][0] = s; red[w][i * 16 + lg * 4 + q][1] = ss; }
        }
    __syncthreads();
    if (tid < 64) {
        float s = red[0][tid][0] + red[1][tid][0] + red[2][tid][0] + red[3][tid][0];
        float ss = red[0][tid][1] + red[1][tid][1] + red[2][tid][1] + red[3][tid][1];
        float mean = s * (1.f / 256.f);
        float var = ss * (1.f / 256.f) - mean * mean;
        mstd[tid] = make_float2(mean, rsqrtf(var + kEps));
    }
    __syncthreads();
    #pragma unroll
    for (int i = 0; i < 4; ++i)
        #pragma unroll
        for (int j = 0; j < 4; ++j) {
            int oc = w * 64 + j * 16 + lr;
            #pragma unroll
            for (int q = 0; q < 4; ++q) {
                int nn = i * 16 + lg * 4 + q;
                int node = n0 + nn;
                if (node < kN) {
                    float2 ms = mstd[nn];
                    float o = (acc[i][j][q] - ms.x) * ms.y * gv[j] + bvn[j];
                    x[(size_t)node * kH + oc] = o;
                    x_bf[(size_t)node * kH + oc] = f2bf(o);
                }
            }
        }
}

// ---------------- fused pooling + readout ----------------------------------
__device__ __forceinline__ int lower_bound_i(const int* a, int n, int v) {
    int lo = 0, hi = n;
    while (lo < hi) { int m = (lo + hi) >> 1; if (a[m] < v) lo = m + 1; else hi = m; }
    return lo;
}

__global__ __launch_bounds__(256) void k_pool_ro(
    const float* __restrict__ x, const int* __restrict__ batch,
    const float* __restrict__ W1, const float* __restrict__ b1,
    const float* __restrict__ W2, const float* __restrict__ b2,
    float* __restrict__ out)
{
    __shared__ float ph[kH];
    __shared__ float h1[kH];
    const int b = blockIdx.x, t = threadIdx.x;
    const int s = lower_bound_i(batch, kN, b);
    const int e = lower_bound_i(batch, kN, b + 1);
    float acc = 0.f;
    for (int i = s; i < e; ++i) acc += x[(size_t)i * kH + t];
    ph[t] = acc / (float)(e - s);
    __syncthreads();
    float a = b1[t];
    for (int k = 0; k < kH; ++k) a = fmaf(ph[k], W1[k * kH + t], a);
    h1[t] = a > 0.f ? a : 0.f;
    __syncthreads();
    if (t < kC) {
        float o = b2[t];
        for (int k = 0; k < kH; ++k) o = fmaf(h1[k], W2[k * kC + t], o);
        out[b * kC + t] = o;
    }
}

// ---------------- launch ---------------------------------------------------
extern "C" void kernel_launch(void* const* d_in, const int* in_sizes, int n_in,
                              void* d_out, int out_size, void* d_ws, size_t ws_size,
                              hipStream_t stream)
{
    const float* nf     = (const float*)d_in[0];
    const void*  ei_raw = d_in[1];
    const float* ef     = (const float*)d_in[2];
    const void*  ba_raw = d_in[3];
    const float* node_W = (const float*)d_in[4];
    const float* node_b = (const float*)d_in[5];
    const float* edge_W = (const float*)d_in[6];
    const float* edge_b = (const float*)d_in[7];
    const float* msg_W1 = (const float*)d_in[8];
    const float* msg_b1 = (const float*)d_in[9];
    const float* msg_W2 = (const float*)d_in[10];
    const float* msg_b2 = (const float*)d_in[11];
    const float* upd_W1 = (const float*)d_in[12];
    const float* upd_b1 = (const float*)d_in[13];
    const float* upd_W2 = (const float*)d_in[14];
    const float* upd_b2 = (const float*)d_in[15];
    const float* ln_g   = (const float*)d_in[16];
    const float* ln_b   = (const float*)d_in[17];
    const float* ro_W1  = (const float*)d_in[18];
    const float* ro_b1  = (const float*)d_in[19];
    const float* ro_W2  = (const float*)d_in[20];
    const float* ro_b2  = (const float*)d_in[21];

    char* p = (char*)d_ws;
    auto alloc = [&](size_t bytes) { char* r = p; p += (bytes + 255) & ~(size_t)255; return r; };
    float* x    = (float*)alloc((size_t)kN * kH * 4);
    float* agg  = (float*)alloc((size_t)kN * kH * 4);
    u16* x_bf   = (u16*)alloc((size_t)kN * kH * 2);
    u16* y_a    = (u16*)alloc((size_t)kN * kH * 2);
    u16* y_b    = (u16*)alloc((size_t)kN * kH * 2);
    u16* tm1 = (u16*)alloc((size_t)kL * 768 * 256 * 2);
    u16* tm2 = (u16*)alloc((size_t)kL * 256 * 256 * 2);
    u16* tu1 = (u16*)alloc((size_t)kL * 512 * 256 * 2);
    u16* tu2 = (u16*)alloc((size_t)kL * 256 * 256 * 2);
    u16* tmc = (u16*)alloc((size_t)kL * 64 * 256 * 2);
    float* b1p = (float*)alloc((size_t)kL * 256 * 4);
    int* ei32 = (int*)alloc((size_t)2 * kE * 4);
    int* ba32 = (int*)alloc((size_t)kN * 4);
    int* cnt  = (int*)alloc((size_t)kN * 4);
    int* cur  = (int*)alloc((size_t)kN * 4);
    int* perm = (int*)alloc((size_t)kE * 4);
    int* ssorted = (int*)alloc((size_t)kE * 4);
    int* dsorted = (int*)alloc((size_t)kE * 4);
    int* flag = (int*)alloc(4);

    k_detect_i64<<<1, 64, 0, stream>>>((const unsigned*)ei_raw, flag);
    k_cvt_idx<<<(2 * kE + 255) / 256, 256, 0, stream>>>((const unsigned*)ei_raw, flag, ei32, 2 * kE);
    k_cvt_idx<<<(kN + 255) / 256, 256, 0, stream>>>((const unsigned*)ba_raw, flag, ba32, kN);
    const int* src = ei32;
    const int* dst = ei32 + kE;

    hipMemsetAsync(cnt, 0, (size_t)kN * 4, stream);
    k_hist<<<(kE + 255) / 256, 256, 0, stream>>>(dst, cnt);
    k_scan<<<1, 256, 0, stream>>>(cnt, cur);
    k_scatter<<<(kE + 255) / 256, 256, 0, stream>>>(src, dst, cur, perm, ssorted, dsorted);

    const int prep_elems = kL * (768 + 256 + 512 + 256) * 256;
    k_prep_w<<<(prep_elems + 255) / 256, 256, 0, stream>>>(
        msg_W1, msg_W2, upd_W1, upd_W2, tm1, tm2, tu1, tu2);
    k_prep_m<<<dim3(kL, 4), 256, 0, stream>>>(edge_W, edge_b, msg_W1, msg_b1, tmc, b1p);

    k_encode_nodes<<<kN / 4, 256, 0, stream>>>(nf, node_W, node_b, x, x_bf);

    hipMemsetAsync(agg, 0, (size_t)kN * kH * sizeof(float), stream);
    for (int l = 0; l < kL; ++l) {
        k_node_pre<<<dim3((kN + 63) / 64, 2), 256, 0, stream>>>(
            x_bf, tm1 + (size_t)l * 768 * 256, y_a, y_b);
        k_msg<<<kE / 64, 256, 0, stream>>>(ef, ssorted, dsorted, perm, y_a, y_b,
            tmc + (size_t)l * 64 * 256, b1p + l * 256,
            tm2 + (size_t)l * 256 * 256, msg_b2 + l * kH, agg);
        k_upd<<<(kN + 63) / 64, 256, 0, stream>>>(x, x_bf, agg,
            tu1 + (size_t)l * 512 * 256, upd_b1 + l * kH,
            tu2 + (size_t)l * 256 * 256, upd_b2 + l * kH,
            ln_g + l * kH, ln_b + l * kH);
    }

    k_pool_ro<<<kB, 256, 0, stream>>>(x, ba32, ro_W1, ro_b1, ro_W2, ro_b2, (float*)d_out);
}